// Round 10
// baseline (227.139 us; speedup 1.0000x reference)
//
#include <hip/hip_runtime.h>

#define BATCH 4
#define SEQ   4096
#define DIM   1024
#define NCH   512
#define CHK   8
#define NROWS (BATCH*SEQ)
#define NKT   32            // gemm K-tiles (1024/32)

typedef __attribute__((ext_vector_type(4))) float f32x4;
typedef __attribute__((ext_vector_type(8))) short shortx8;
typedef __attribute__((ext_vector_type(4))) short shortx4;

static __device__ __forceinline__ unsigned short f2bf(float f){
    unsigned int u = __float_as_uint(f);
    u += 0x7FFFu + ((u >> 16) & 1u);
    return (unsigned short)(u >> 16);
}
static __device__ __forceinline__ float bf2f(unsigned short h){
    return __uint_as_float(((unsigned int)h) << 16);
}
static __device__ __forceinline__ float sigmoidf_fast(float x){
    return 1.0f / (1.0f + __expf(-x));
}
static __device__ __forceinline__ shortx4 pack4(f32x4 s){
    shortx4 o;
    o.x = (short)f2bf(s.x); o.y = (short)f2bf(s.y);
    o.z = (short)f2bf(s.z); o.w = (short)f2bf(s.w);
    return o;
}
static __device__ __forceinline__ f32x4 unpack4(shortx4 s){
    f32x4 o;
    o.x = bf2f((unsigned short)s.x); o.y = bf2f((unsigned short)s.y);
    o.z = bf2f((unsigned short)s.z); o.w = bf2f((unsigned short)s.w);
    return o;
}

// ---------------- K1: shift + decay + exp + chunk-local scan (+ fused W-pack) ----
__global__ __launch_bounds__(256) void k_shift_scan(
    const float* __restrict__ X, const float* __restrict__ XP,
    const float* __restrict__ mu_p, const float* __restrict__ dw,
    const float* __restrict__ db_p,
    const float* __restrict__ Wr, const float* __restrict__ Wv,
    unsigned short* __restrict__ Wcat,
    unsigned short* __restrict__ shifted,
    unsigned short* __restrict__ b_local, float* __restrict__ a_local,
    float* __restrict__ cumP)
{
    const int tid  = threadIdx.x;

    if (blockIdx.x >= 512){            // ---- weight pack path ----
        const int pb = blockIdx.x - 512;       // 0..63
        #pragma unroll 4
        for (int i = 0; i < 32; ++i){
            const int n = pb*32 + i;
            const int grp = n >> 5, r = n & 31;
            const float* src = (r < 16) ? (Wr + (size_t)(grp*16 + r)*DIM)
                                        : (Wv + (size_t)(grp*16 + (r-16))*DIM);
            f32x4 v = reinterpret_cast<const f32x4*>(src)[tid];
            reinterpret_cast<shortx4*>(Wcat)[n*256 + tid] = pack4(v);
        }
        return;
    }

    const int lane = tid & 63;
    const int wid  = tid >> 6;
    const int cid  = blockIdx.x*4 + wid;
    const int batch = cid >> 9;
    const int chunk = cid & (NCH-1);
    const int row0  = batch*SEQ + chunk*CHK;

    const float mu = mu_p[0];
    const float om = 1.0f - mu;
    const float db = db_p[0];

    const f32x4* dwv = reinterpret_cast<const f32x4*>(dw);
    const f32x4 w0 = dwv[lane], w1 = dwv[64+lane], w2 = dwv[128+lane], w3 = dwv[192+lane];

    f32x4 b0 = {0,0,0,0}, b1 = {0,0,0,0}, b2 = {0,0,0,0}, b3 = {0,0,0,0};
    float a_run = 0.f, cp = 1.f;

    const f32x4* Xv  = reinterpret_cast<const f32x4*>(X);
    const f32x4* XPv = reinterpret_cast<const f32x4*>(XP);
    shortx4* BL = reinterpret_cast<shortx4*>(b_local);
    shortx4* SH = reinterpret_cast<shortx4*>(shifted);

    for (int r = 0; r < CHK; ++r){
        const int row = row0 + r;
        const int rb  = row*(DIM/4);

        f32x4 x0 = Xv[rb+lane],     x1 = Xv[rb+64+lane],
              x2 = Xv[rb+128+lane], x3 = Xv[rb+192+lane];
        f32x4 p0 = XPv[rb+lane],     p1 = XPv[rb+64+lane],
              p2 = XPv[rb+128+lane], p3 = XPv[rb+192+lane];
        f32x4 s0 = mu*x0 + om*p0, s1 = mu*x1 + om*p1;
        f32x4 s2 = mu*x2 + om*p2, s3 = mu*x3 + om*p3;

        SH[rb+lane]     = pack4(s0);
        SH[rb+64+lane]  = pack4(s1);
        SH[rb+128+lane] = pack4(s2);
        SH[rb+192+lane] = pack4(s3);

        float dot = s0.x*w0.x + s0.y*w0.y + s0.z*w0.z + s0.w*w0.w
                  + s1.x*w1.x + s1.y*w1.y + s1.z*w1.z + s1.w*w1.w
                  + s2.x*w2.x + s2.y*w2.y + s2.z*w2.z + s2.w*w2.w
                  + s3.x*w3.x + s3.y*w3.y + s3.z*w3.z + s3.w*w3.w;

        f32x4 e0, e1, e2, e3;
        e0.x=__expf(s0.x); e0.y=__expf(s0.y); e0.z=__expf(s0.z); e0.w=__expf(s0.w);
        e1.x=__expf(s1.x); e1.y=__expf(s1.y); e1.z=__expf(s1.z); e1.w=__expf(s1.w);
        e2.x=__expf(s2.x); e2.y=__expf(s2.y); e2.z=__expf(s2.z); e2.w=__expf(s2.w);
        e3.x=__expf(s3.x); e3.y=__expf(s3.y); e3.z=__expf(s3.z); e3.w=__expf(s3.w);
        float ea = e0.x+e0.y+e0.z+e0.w + e1.x+e1.y+e1.z+e1.w
                 + e2.x+e2.y+e2.z+e2.w + e3.x+e3.y+e3.z+e3.w;

        #pragma unroll
        for (int off = 1; off < 64; off <<= 1){
            dot += __shfl_xor(dot, off, 64);
            ea  += __shfl_xor(ea,  off, 64);
        }

        const float dt = sigmoidf_fast(dot + db);
        a_run = dt*a_run + ea;
        cp   *= dt;
        b0 = dt*b0 + e0*s0;  b1 = dt*b1 + e1*s1;
        b2 = dt*b2 + e2*s2;  b3 = dt*b3 + e3*s3;

        BL[rb+lane]     = pack4(b0);
        BL[rb+64+lane]  = pack4(b1);
        BL[rb+128+lane] = pack4(b2);
        BL[rb+192+lane] = pack4(b3);
        if (lane == 0){ a_local[row] = a_run; cumP[row] = cp; }
    }
}

// ---------------- K2: sequential carry combine (depth-16 vector prefetch) ----
__global__ __launch_bounds__(64) void k_combine(
    const unsigned short* __restrict__ b_local, const float* __restrict__ a_local,
    const float* __restrict__ cumP,
    float* __restrict__ carryA, unsigned short* __restrict__ carryB)
{
    const int batch = blockIdx.x >> 2;
    const int dseg  = blockIdx.x & 3;
    const int tid = threadIdx.x;
    const int d0 = dseg*256 + tid*4;

    __shared__ float sP[NCH], sA[NCH];
    for (int c = tid; c < NCH; c += 64){
        const int er = batch*SEQ + c*CHK + (CHK-1);
        sP[c] = cumP[er];
        sA[c] = a_local[er];
    }
    __syncthreads();

    const unsigned short* bl = b_local + (size_t)batch*SEQ*DIM + d0;
    unsigned short* cB = carryB + (size_t)batch*NCH*DIM + d0;
    const bool wA = (dseg == 0 && tid == 0);
    float* cAp = carryA + batch*NCH;

    shortx4 pf[16];
    #pragma unroll
    for (int i = 0; i < 16; ++i)
        pf[i] = *reinterpret_cast<const shortx4*>(bl + (i*CHK + CHK-1)*DIM);

    f32x4 cb = {0,0,0,0};
    float ca = 0.f;

    for (int cc = 0; cc < NCH; cc += 16){
        const bool more = (cc + 16 < NCH);
        #pragma unroll
        for (int k = 0; k < 16; ++k){
            const int c = cc + k;
            f32x4 v = unpack4(pf[k]);
            if (more)
                pf[k] = *reinterpret_cast<const shortx4*>(bl + ((c+16)*CHK + CHK-1)*DIM);
            *reinterpret_cast<shortx4*>(cB + (size_t)c*DIM) = pack4(cb);
            if (wA) cAp[c] = ca;
            const float p = sP[c];
            cb = p*cb + v;
            ca = p*ca + sA[c];
        }
    }
}

// ---------------- K3: carry fixup + divide + LN1 -> merged (wave-per-row) ----
__global__ __launch_bounds__(256) void k_fix_ln1(
    const unsigned short* __restrict__ b_local, const float* __restrict__ a_local,
    const float* __restrict__ cumP, const float* __restrict__ carryA,
    const unsigned short* __restrict__ carryB,
    const float* __restrict__ g1, const float* __restrict__ bb1,
    unsigned short* __restrict__ merged)
{
    const int tid = threadIdx.x, lane = tid & 63, wid = tid >> 6;
    const int row = blockIdx.x*4 + wid;
    const int batch = row >> 12;
    const int c = (row & (SEQ-1)) >> 3;

    const float cpv = cumP[row];
    const float a = a_local[row] + cpv * carryA[batch*NCH + c];
    const float inv_a = 1.0f / (a + 1e-8f);

    const shortx4* BL = reinterpret_cast<const shortx4*>(b_local) + (size_t)row*256;
    const shortx4* CB = reinterpret_cast<const shortx4*>(carryB) + (size_t)(batch*NCH + c)*256;

    f32x4 o[4];
    float s = 0.f, s2 = 0.f;
    #pragma unroll
    for (int j = 0; j < 4; ++j){
        f32x4 bl = unpack4(BL[j*64 + lane]);
        f32x4 cb = unpack4(CB[j*64 + lane]);
        f32x4 v = (bl + cpv*cb) * inv_a;
        o[j] = v;
        s  += v.x+v.y+v.z+v.w;
        s2 += v.x*v.x + v.y*v.y + v.z*v.z + v.w*v.w;
    }
    #pragma unroll
    for (int off = 1; off < 64; off <<= 1){
        s  += __shfl_xor(s,  off, 64);
        s2 += __shfl_xor(s2, off, 64);
    }
    const float mean = s * (1.0f/DIM);
    const float rstd = rsqrtf(s2*(1.0f/DIM) - mean*mean + 1e-5f);
    shortx4* MG = reinterpret_cast<shortx4*>(merged) + (size_t)row*256;
    #pragma unroll
    for (int j = 0; j < 4; ++j){
        f32x4 gg = reinterpret_cast<const f32x4*>(g1)[j*64 + lane];
        f32x4 bb = reinterpret_cast<const f32x4*>(bb1)[j*64 + lane];
        MG[j*64 + lane] = pack4((o[j] - mean)*rstd*gg + bb);
    }
}

// ---------------- K5: fat-wave 256x256 bf16 GEMM (4 waves, 2 blocks/CU) ------
// 256 thr = 4 waves (wm=wid>>1, wn=wid&1), per-wave C = 128x128 (acc[8][8],
// ~350 VGPR). BK=32, dbuf 2x32KB -> LDS 69.6KB -> 2 INDEPENDENT blocks/CU:
// block A's MFMA overlaps block B's LDS reads/stage (m114 mechanism) without
// intra-block schedule heroics. Per-wave per tile: 16 ds_read_b128 for 64
// independent MFMA (1:4 read:mfma, 1.5x less LDS traffic than 8-wave split).
// Grid 512 = 1 round. Subtile 16x32 bf16 swizzle (cg^=2 @ row&8) unchanged.
typedef __attribute__((address_space(3))) unsigned int lds_uint;
typedef __attribute__((address_space(1))) unsigned int glob_uint;
static __device__ __forceinline__ void gload16(const unsigned short* g, char* l){
    __builtin_amdgcn_global_load_lds((const glob_uint*)g, (lds_uint*)l, 16, 0, 0);
}
#define SBAR() do { __builtin_amdgcn_sched_barrier(0); __builtin_amdgcn_s_barrier(); __builtin_amdgcn_sched_barrier(0); } while(0)
#define LGKM0() do { asm volatile("s_waitcnt lgkmcnt(0)" ::: "memory"); __builtin_amdgcn_sched_barrier(0); } while(0)
#define VMC(n)  do { asm volatile("s_waitcnt vmcnt(" #n ")" ::: "memory"); __builtin_amdgcn_sched_barrier(0); } while(0)
#define LDSE 136

__global__ __launch_bounds__(256, 1) void k_gemm(
    const unsigned short* __restrict__ A,    // merged bf16 [16384][1024]
    const unsigned short* __restrict__ Bt,   // Wcat  bf16 [2048][1024]
    const float* __restrict__ rbias, const float* __restrict__ vbias,
    unsigned short* __restrict__ gv)         // bf16 [16384][1024]
{
    __shared__ __align__(16) char lds[69632];   // 2 x 32KB dbuf; epilogue 128x136x2
    const int tid  = threadIdx.x;
    const int lane = tid & 63;
    const int wid  = tid >> 6;       // 0..3
    const int wm   = wid >> 1;       // 0..1 (row half)
    const int wn   = wid & 1;        // 0..1 (col half)

    const int bid  = blockIdx.x;
    const int wgid = (bid & 7)*64 + (bid >> 3);
    const int mt = wgid >> 3, nt = wgid & 7;
    const int m0 = mt*256, n0 = nt*256;

    // staging source (pre-swizzled col-group); wave stages subtiles 4w..4w+3
    const int rin = lane >> 2;
    const int scg = (lane & 3) ^ (((lane >> 5) & 1) << 1);
    const unsigned short* gA = A  + (size_t)(m0 + wid*64 + rin)*DIM + scg*8;
    const unsigned short* gB = Bt + (size_t)(n0 + wid*64 + rin)*DIM + scg*8;

    // fragment read offset (matching swizzle)
    const int fr = lane & 15, fq = lane >> 4;
    const int soff = fr*64 + ((fq*16) ^ ((fr & 8) ? 32 : 0));

    f32x4 acc[8][8];
    #pragma unroll
    for (int i = 0; i < 8; ++i)
        #pragma unroll
        for (int j = 0; j < 8; ++j) acc[i][j] = (f32x4){0,0,0,0};

    auto STAGE = [&](int tk){        // 8 gloads: 4 A-subtiles + 4 B-subtiles
        char* base = lds + (tk & 1)*32768;
        const unsigned short* sa = gA + tk*32;
        const unsigned short* sb = gB + tk*32;
        #pragma unroll
        for (int s = 0; s < 4; ++s){
            gload16(sa + (size_t)(s*16)*DIM, base + (wid*4 + s)*1024);
            gload16(sb + (size_t)(s*16)*DIM, base + 16384 + (wid*4 + s)*1024);
        }
    };

    shortx8 af[8], bf[8];

    // prologue: tiles 0,1 staged; own tile-0 gloads landed; all waves synced
    STAGE(0); STAGE(1);
    VMC(8);
    SBAR();

    for (int T = 0; T < NKT; ++T){
        const char* base = lds + (T & 1)*32768;

        // 16 ds_read_b128: A m-frags (wm half) + B n-frags (wn half)
        #pragma unroll
        for (int m = 0; m < 8; ++m)
            af[m] = *reinterpret_cast<const shortx8*>(base + (wm*8 + m)*1024 + soff);
        #pragma unroll
        for (int n = 0; n < 8; ++n)
            bf[n] = *reinterpret_cast<const shortx8*>(base + 16384 + (wn*8 + n)*1024 + soff);
        LGKM0();                 // fragments in regs
        SBAR();                  // all waves done reading buf[T&1] -> overwritable

        if (T + 2 < NKT) STAGE(T + 2);   // 8 gloads fly under the MFMA cluster

        __builtin_amdgcn_s_setprio(1);
        #pragma unroll
        for (int m = 0; m < 8; ++m)
            #pragma unroll
            for (int n = 0; n < 8; ++n)
                acc[m][n] = __builtin_amdgcn_mfma_f32_16x16x32_bf16(af[m], bf[n], acc[m][n], 0, 0, 0);
        __builtin_amdgcn_s_setprio(0);

        if (T + 1 < NKT){
            if (T + 2 < NKT) { VMC(8); } else { VMC(0); }   // tile T+1 landed (own)
            SBAR();                                          // ...and all waves'
        }
    }

    // ---- epilogue: sigmoid(gate)*value -> padded LDS transpose, 2 row-halves --
    // e-col pairing: n even = gate, n odd = value for block-ecol wn*64+(n>>1)*16+fr
    #pragma unroll
    for (int half = 0; half < 2; ++half){
        __syncthreads();
        unsigned short* ep = reinterpret_cast<unsigned short*>(lds);  // [128][LDSE]
        if (wm == half){
            #pragma unroll
            for (int j = 0; j < 4; ++j){
                const int ecol = wn*64 + j*16 + fr;
                const float rbe = rbias[nt*128 + ecol];
                const float vbe = vbias[nt*128 + ecol];
                #pragma unroll
                for (int m = 0; m < 8; ++m){
                    const int rbase = m*16 + fq*4;
                    f32x4 ga = acc[m][2*j], va = acc[m][2*j+1];
                    #pragma unroll
                    for (int q = 0; q < 4; ++q){
                        const float g = sigmoidf_fast(ga[q] + rbe);
                        ep[(rbase + q)*LDSE + ecol] = f2bf(g*(va[q] + vbe));
                    }
                }
            }
        }
        __syncthreads();
        #pragma unroll
        for (int p = 0; p < 8; ++p){
            const int r  = p*16 + (tid >> 4);
            const int c8 = tid & 15;
            shortx8 val = *reinterpret_cast<const shortx8*>(&ep[r*LDSE + c8*8]);
            *reinterpret_cast<shortx8*>(
                &gv[(size_t)(m0 + half*128 + r)*DIM + nt*128 + c8*8]) = val;
        }
    }
}

// ---------------- K6: LN2 + residual (wave-per-row) ----------------
__global__ __launch_bounds__(256) void k_ln2_res(
    const unsigned short* __restrict__ gvb, const unsigned short* __restrict__ shifted,
    const float* __restrict__ g2, const float* __restrict__ b2,
    float* __restrict__ out)
{
    const int tid = threadIdx.x, lane = tid & 63, wid = tid >> 6;
    const int row = blockIdx.x*4 + wid;

    const shortx4* GV = reinterpret_cast<const shortx4*>(gvb) + (size_t)row*256;
    const shortx4* SH = reinterpret_cast<const shortx4*>(shifted) + (size_t)row*256;

    f32x4 v[4];
    float s = 0.f, s2 = 0.f;
    #pragma unroll
    for (int j = 0; j < 4; ++j){
        f32x4 x = unpack4(GV[j*64 + lane]);
        v[j] = x;
        s  += x.x+x.y+x.z+x.w;
        s2 += x.x*x.x + x.y*x.y + x.z*x.z + x.w*x.w;
    }
    #pragma unroll
    for (int off = 1; off < 64; off <<= 1){
        s  += __shfl_xor(s,  off, 64);
        s2 += __shfl_xor(s2, off, 64);
    }
    const float mean = s * (1.0f/DIM);
    const float rstd = rsqrtf(s2*(1.0f/DIM) - mean*mean + 1e-5f);
    f32x4* O = reinterpret_cast<f32x4*>(out) + (size_t)row*256;
    #pragma unroll
    for (int j = 0; j < 4; ++j){
        f32x4 gg = reinterpret_cast<const f32x4*>(g2)[j*64 + lane];
        f32x4 bb = reinterpret_cast<const f32x4*>(b2)[j*64 + lane];
        f32x4 sh = unpack4(SH[j*64 + lane]);
        O[j*64 + lane] = sh + (v[j] - mean)*rstd*gg + bb;
    }
}

extern "C" void kernel_launch(void* const* d_in, const int* in_sizes, int n_in,
                              void* d_out, int out_size, void* d_ws, size_t ws_size,
                              hipStream_t stream)
{
    (void)in_sizes; (void)n_in; (void)out_size; (void)ws_size;
    const float* x     = (const float*)d_in[0];
    const float* xprev = (const float*)d_in[1];
    const float* mu    = (const float*)d_in[2];
    const float* dw    = (const float*)d_in[3];
    const float* db    = (const float*)d_in[4];
    const float* ln1g  = (const float*)d_in[5];
    const float* ln1b  = (const float*)d_in[6];
    const float* Wr    = (const float*)d_in[7];
    const float* Wrb   = (const float*)d_in[8];
    const float* Wv    = (const float*)d_in[9];
    const float* Wvb   = (const float*)d_in[10];
    const float* ln2g  = (const float*)d_in[11];
    const float* ln2b  = (const float*)d_in[12];
    float* out = (float*)d_out;

    char* ws = (char*)d_ws;
    size_t off = 0;
    auto alloc = [&](size_t bytes) -> void* {
        void* p = ws + off;
        off += (bytes + 255) & ~(size_t)255;
        return p;
    };
    unsigned short* shifted = (unsigned short*)alloc((size_t)NROWS*DIM*2);
    unsigned short* b_local = (unsigned short*)alloc((size_t)NROWS*DIM*2);
    unsigned short* merged  = (unsigned short*)alloc((size_t)NROWS*DIM*2);
    unsigned short* carryB  = (unsigned short*)alloc((size_t)BATCH*NCH*DIM*2);
    unsigned short* Wcat    = (unsigned short*)alloc((size_t)2048*1024*2);
    float* a_local          = (float*)alloc((size_t)NROWS*4);
    float* cumP             = (float*)alloc((size_t)NROWS*4);
    float* carryA           = (float*)alloc((size_t)BATCH*NCH*4);
    unsigned short* gvbuf   = b_local;   // b_local dead after k_fix_ln1

    hipLaunchKernelGGL(k_shift_scan, dim3(576),  dim3(256), 0, stream,
                       x, xprev, mu, dw, db, Wr, Wv, Wcat, shifted, b_local, a_local, cumP);
    hipLaunchKernelGGL(k_combine,    dim3(16),   dim3(64),  0, stream,
                       b_local, a_local, cumP, carryA, carryB);
    hipLaunchKernelGGL(k_fix_ln1,    dim3(4096), dim3(256), 0, stream,
                       b_local, a_local, cumP, carryA, carryB, ln1g, ln1b, merged);
    hipLaunchKernelGGL(k_gemm,       dim3(512),  dim3(256), 0, stream,
                       merged, Wcat, Wrb, Wvb, gvbuf);
    hipLaunchKernelGGL(k_ln2_res,    dim3(4096), dim3(256), 0, stream,
                       gvbuf, shifted, ln2g, ln2b, out);
}

// Round 11
// 209.282 us; speedup vs baseline: 1.0853x; 1.0853x over previous
//
#include <hip/hip_runtime.h>

#define BATCH 4
#define SEQ   4096
#define DIM   1024
#define NCH   512
#define CHK   8
#define NROWS (BATCH*SEQ)
#define NKT   32            // gemm K-tiles (1024/32)

typedef __attribute__((ext_vector_type(4))) float f32x4;
typedef __attribute__((ext_vector_type(8))) short shortx8;
typedef __attribute__((ext_vector_type(4))) short shortx4;

static __device__ __forceinline__ unsigned short f2bf(float f){
    unsigned int u = __float_as_uint(f);
    u += 0x7FFFu + ((u >> 16) & 1u);
    return (unsigned short)(u >> 16);
}
static __device__ __forceinline__ float bf2f(unsigned short h){
    return __uint_as_float(((unsigned int)h) << 16);
}
static __device__ __forceinline__ float sigmoidf_fast(float x){
    return 1.0f / (1.0f + __expf(-x));
}
static __device__ __forceinline__ shortx4 pack4(f32x4 s){
    shortx4 o;
    o.x = (short)f2bf(s.x); o.y = (short)f2bf(s.y);
    o.z = (short)f2bf(s.z); o.w = (short)f2bf(s.w);
    return o;
}
static __device__ __forceinline__ f32x4 unpack4(shortx4 s){
    f32x4 o;
    o.x = bf2f((unsigned short)s.x); o.y = bf2f((unsigned short)s.y);
    o.z = bf2f((unsigned short)s.z); o.w = bf2f((unsigned short)s.w);
    return o;
}

// ---------------- K1: shift + decay + exp + chunk-local scan (+ fused W-pack) ----
__global__ __launch_bounds__(256) void k_shift_scan(
    const float* __restrict__ X, const float* __restrict__ XP,
    const float* __restrict__ mu_p, const float* __restrict__ dw,
    const float* __restrict__ db_p,
    const float* __restrict__ Wr, const float* __restrict__ Wv,
    unsigned short* __restrict__ Wcat,
    unsigned short* __restrict__ shifted,
    unsigned short* __restrict__ b_local, float* __restrict__ a_local,
    float* __restrict__ cumP)
{
    const int tid  = threadIdx.x;

    if (blockIdx.x >= 512){            // ---- weight pack path ----
        const int pb = blockIdx.x - 512;       // 0..63
        #pragma unroll 4
        for (int i = 0; i < 32; ++i){
            const int n = pb*32 + i;
            const int grp = n >> 5, r = n & 31;
            const float* src = (r < 16) ? (Wr + (size_t)(grp*16 + r)*DIM)
                                        : (Wv + (size_t)(grp*16 + (r-16))*DIM);
            f32x4 v = reinterpret_cast<const f32x4*>(src)[tid];
            reinterpret_cast<shortx4*>(Wcat)[n*256 + tid] = pack4(v);
        }
        return;
    }

    const int lane = tid & 63;
    const int wid  = tid >> 6;
    const int cid  = blockIdx.x*4 + wid;
    const int batch = cid >> 9;
    const int chunk = cid & (NCH-1);
    const int row0  = batch*SEQ + chunk*CHK;

    const float mu = mu_p[0];
    const float om = 1.0f - mu;
    const float db = db_p[0];

    const f32x4* dwv = reinterpret_cast<const f32x4*>(dw);
    const f32x4 w0 = dwv[lane], w1 = dwv[64+lane], w2 = dwv[128+lane], w3 = dwv[192+lane];

    f32x4 b0 = {0,0,0,0}, b1 = {0,0,0,0}, b2 = {0,0,0,0}, b3 = {0,0,0,0};
    float a_run = 0.f, cp = 1.f;

    const f32x4* Xv  = reinterpret_cast<const f32x4*>(X);
    const f32x4* XPv = reinterpret_cast<const f32x4*>(XP);
    shortx4* BL = reinterpret_cast<shortx4*>(b_local);
    shortx4* SH = reinterpret_cast<shortx4*>(shifted);

    for (int r = 0; r < CHK; ++r){
        const int row = row0 + r;
        const int rb  = row*(DIM/4);

        f32x4 x0 = Xv[rb+lane],     x1 = Xv[rb+64+lane],
              x2 = Xv[rb+128+lane], x3 = Xv[rb+192+lane];
        f32x4 p0 = XPv[rb+lane],     p1 = XPv[rb+64+lane],
              p2 = XPv[rb+128+lane], p3 = XPv[rb+192+lane];
        f32x4 s0 = mu*x0 + om*p0, s1 = mu*x1 + om*p1;
        f32x4 s2 = mu*x2 + om*p2, s3 = mu*x3 + om*p3;

        SH[rb+lane]     = pack4(s0);
        SH[rb+64+lane]  = pack4(s1);
        SH[rb+128+lane] = pack4(s2);
        SH[rb+192+lane] = pack4(s3);

        float dot = s0.x*w0.x + s0.y*w0.y + s0.z*w0.z + s0.w*w0.w
                  + s1.x*w1.x + s1.y*w1.y + s1.z*w1.z + s1.w*w1.w
                  + s2.x*w2.x + s2.y*w2.y + s2.z*w2.z + s2.w*w2.w
                  + s3.x*w3.x + s3.y*w3.y + s3.z*w3.z + s3.w*w3.w;

        f32x4 e0, e1, e2, e3;
        e0.x=__expf(s0.x); e0.y=__expf(s0.y); e0.z=__expf(s0.z); e0.w=__expf(s0.w);
        e1.x=__expf(s1.x); e1.y=__expf(s1.y); e1.z=__expf(s1.z); e1.w=__expf(s1.w);
        e2.x=__expf(s2.x); e2.y=__expf(s2.y); e2.z=__expf(s2.z); e2.w=__expf(s2.w);
        e3.x=__expf(s3.x); e3.y=__expf(s3.y); e3.z=__expf(s3.z); e3.w=__expf(s3.w);
        float ea = e0.x+e0.y+e0.z+e0.w + e1.x+e1.y+e1.z+e1.w
                 + e2.x+e2.y+e2.z+e2.w + e3.x+e3.y+e3.z+e3.w;

        #pragma unroll
        for (int off = 1; off < 64; off <<= 1){
            dot += __shfl_xor(dot, off, 64);
            ea  += __shfl_xor(ea,  off, 64);
        }

        const float dt = sigmoidf_fast(dot + db);
        a_run = dt*a_run + ea;
        cp   *= dt;
        b0 = dt*b0 + e0*s0;  b1 = dt*b1 + e1*s1;
        b2 = dt*b2 + e2*s2;  b3 = dt*b3 + e3*s3;

        BL[rb+lane]     = pack4(b0);
        BL[rb+64+lane]  = pack4(b1);
        BL[rb+128+lane] = pack4(b2);
        BL[rb+192+lane] = pack4(b3);
        if (lane == 0){ a_local[row] = a_run; cumP[row] = cp; }
    }
}

// ---------------- K2: sequential carry combine (depth-16 vector prefetch) ----
__global__ __launch_bounds__(64) void k_combine(
    const unsigned short* __restrict__ b_local, const float* __restrict__ a_local,
    const float* __restrict__ cumP,
    float* __restrict__ carryA, unsigned short* __restrict__ carryB)
{
    const int batch = blockIdx.x >> 2;
    const int dseg  = blockIdx.x & 3;
    const int tid = threadIdx.x;
    const int d0 = dseg*256 + tid*4;

    __shared__ float sP[NCH], sA[NCH];
    for (int c = tid; c < NCH; c += 64){
        const int er = batch*SEQ + c*CHK + (CHK-1);
        sP[c] = cumP[er];
        sA[c] = a_local[er];
    }
    __syncthreads();

    const unsigned short* bl = b_local + (size_t)batch*SEQ*DIM + d0;
    unsigned short* cB = carryB + (size_t)batch*NCH*DIM + d0;
    const bool wA = (dseg == 0 && tid == 0);
    float* cAp = carryA + batch*NCH;

    shortx4 pf[16];
    #pragma unroll
    for (int i = 0; i < 16; ++i)
        pf[i] = *reinterpret_cast<const shortx4*>(bl + (i*CHK + CHK-1)*DIM);

    f32x4 cb = {0,0,0,0};
    float ca = 0.f;

    for (int cc = 0; cc < NCH; cc += 16){
        const bool more = (cc + 16 < NCH);
        #pragma unroll
        for (int k = 0; k < 16; ++k){
            const int c = cc + k;
            f32x4 v = unpack4(pf[k]);
            if (more)
                pf[k] = *reinterpret_cast<const shortx4*>(bl + ((c+16)*CHK + CHK-1)*DIM);
            *reinterpret_cast<shortx4*>(cB + (size_t)c*DIM) = pack4(cb);
            if (wA) cAp[c] = ca;
            const float p = sP[c];
            cb = p*cb + v;
            ca = p*ca + sA[c];
        }
    }
}

// ---------------- K3: carry fixup + divide + LN1 -> merged (wave-per-row) ----
__global__ __launch_bounds__(256) void k_fix_ln1(
    const unsigned short* __restrict__ b_local, const float* __restrict__ a_local,
    const float* __restrict__ cumP, const float* __restrict__ carryA,
    const unsigned short* __restrict__ carryB,
    const float* __restrict__ g1, const float* __restrict__ bb1,
    unsigned short* __restrict__ merged)
{
    const int tid = threadIdx.x, lane = tid & 63, wid = tid >> 6;
    const int row = blockIdx.x*4 + wid;
    const int batch = row >> 12;
    const int c = (row & (SEQ-1)) >> 3;

    const float cpv = cumP[row];
    const float a = a_local[row] + cpv * carryA[batch*NCH + c];
    const float inv_a = 1.0f / (a + 1e-8f);

    const shortx4* BL = reinterpret_cast<const shortx4*>(b_local) + (size_t)row*256;
    const shortx4* CB = reinterpret_cast<const shortx4*>(carryB) + (size_t)(batch*NCH + c)*256;

    f32x4 o[4];
    float s = 0.f, s2 = 0.f;
    #pragma unroll
    for (int j = 0; j < 4; ++j){
        f32x4 bl = unpack4(BL[j*64 + lane]);
        f32x4 cb = unpack4(CB[j*64 + lane]);
        f32x4 v = (bl + cpv*cb) * inv_a;
        o[j] = v;
        s  += v.x+v.y+v.z+v.w;
        s2 += v.x*v.x + v.y*v.y + v.z*v.z + v.w*v.w;
    }
    #pragma unroll
    for (int off = 1; off < 64; off <<= 1){
        s  += __shfl_xor(s,  off, 64);
        s2 += __shfl_xor(s2, off, 64);
    }
    const float mean = s * (1.0f/DIM);
    const float rstd = rsqrtf(s2*(1.0f/DIM) - mean*mean + 1e-5f);
    shortx4* MG = reinterpret_cast<shortx4*>(merged) + (size_t)row*256;
    #pragma unroll
    for (int j = 0; j < 4; ++j){
        f32x4 gg = reinterpret_cast<const f32x4*>(g1)[j*64 + lane];
        f32x4 bb = reinterpret_cast<const f32x4*>(bb1)[j*64 + lane];
        MG[j*64 + lane] = pack4((o[j] - mean)*rstd*gg + bb);
    }
}

// ---------------- K5: 256x128 bf16 GEMM, 2 blocks/CU (cross-block overlap) ---
// BM=256, BN=128, BK=32. 8 waves as 4m x 2n; per-wave C = 64x64 (acc[4][4],
// ~96 VGPR; __launch_bounds__(512,4) caps at 128 -> 16 waves/CU = 2 blocks).
// LDS ring-3 x 24KB = 72KB/block -> 2 blocks co-resident (144KB <= 160KB).
// Per tile: STAGE(T+2) (3 gloads/thr) -> 8 ds_read_b128 -> lgkm(0) ->
// 16 MFMA -> vmcnt(3) (own T+1 stages landed, in-order retire) -> s_barrier.
// Cross-block skew overlaps one block's MFMA with the other's LDS reads
// (m114 mechanism) - no intra-block pipeline heroics needed.
typedef __attribute__((address_space(3))) unsigned int lds_uint;
typedef __attribute__((address_space(1))) unsigned int glob_uint;
static __device__ __forceinline__ void gload16(const unsigned short* g, char* l){
    __builtin_amdgcn_global_load_lds((const glob_uint*)g, (lds_uint*)l, 16, 0, 0);
}
#define SBAR() do { __builtin_amdgcn_sched_barrier(0); __builtin_amdgcn_s_barrier(); __builtin_amdgcn_sched_barrier(0); } while(0)
#define LGKM0() do { asm volatile("s_waitcnt lgkmcnt(0)" ::: "memory"); __builtin_amdgcn_sched_barrier(0); } while(0)
#define VMC(n)  do { asm volatile("s_waitcnt vmcnt(" #n ")" ::: "memory"); __builtin_amdgcn_sched_barrier(0); } while(0)
#define LDSE 72    // epilogue row stride (shorts): 64 + 8 pad

__global__ __launch_bounds__(512, 4) void k_gemm(
    const unsigned short* __restrict__ A,    // merged bf16 [16384][1024]
    const unsigned short* __restrict__ Bt,   // Wcat  bf16 [2048][1024]
    const float* __restrict__ rbias, const float* __restrict__ vbias,
    unsigned short* __restrict__ gv)         // bf16 [16384][1024]
{
    __shared__ __align__(16) char lds[73728];   // 3 x 24KB ring; epilogue 256x72x2
    const int tid  = threadIdx.x;
    const int lane = tid & 63;
    const int wid  = tid >> 6;       // 0..7
    const int wm   = wid >> 1;       // 0..3 (64-row slice)
    const int wn   = wid & 1;        // 0..1 (64-col slice of BN=128)

    // bijective XCD swizzle (nwg=1024 % 8 == 0), nt-inner for A-panel L2 reuse
    const int bid  = blockIdx.x;
    const int wgid = (bid & 7)*128 + (bid >> 3);
    const int mt = wgid >> 4, nt = wgid & 15;
    const int m0 = mt*256, n0 = nt*128;

    // staging source (pre-swizzled col-group)
    const int rin = lane >> 2;
    const int scg = (lane & 3) ^ (((lane >> 5) & 1) << 1);
    const unsigned short* pA = A  + (size_t)(m0 + rin)*DIM + scg*8;
    const unsigned short* pB = Bt + (size_t)(n0 + rin)*DIM + scg*8;

    // fragment read offset (matching swizzle)
    const int fr = lane & 15, fq = lane >> 4;
    const int soff = fr*64 + ((fq*16) ^ ((fr & 8) ? 32 : 0));

    f32x4 acc[4][4];
    #pragma unroll
    for (int i = 0; i < 4; ++i)
        #pragma unroll
        for (int j = 0; j < 4; ++j) acc[i][j] = (f32x4){0,0,0,0};

    // stage tile T: 24 subtiles (A 0..15, B 16..23); wave stages 3 (3 gloads/thr)
    auto STAGE = [&](int T){
        if (T >= NKT) return;
        char* base = lds + (T % 3)*24576;
        #pragma unroll
        for (int s = 0; s < 3; ++s){
            const int sub = wid*3 + s;
            const unsigned short* src = (sub < 16)
                ? pA + (size_t)(sub*16)*DIM + T*32
                : pB + (size_t)((sub-16)*16)*DIM + T*32;
            char* dst = base + ((sub < 16) ? sub*1024 : 16384 + (sub-16)*1024);
            gload16(src, dst);
        }
    };

    shortx8 af[4], bf[4];

    // prologue: tiles 0,1 staged (6 gloads/thr); vmcnt(3) -> tile0 landed
    STAGE(0); STAGE(1);
    VMC(3);
    SBAR();

    for (int T = 0; T < NKT; ++T){
        const char* base = lds + (T % 3)*24576;

        STAGE(T + 2);    // slot (T+2)%3 freed by tile T-1 (barrier-confirmed)

        #pragma unroll
        for (int mf = 0; mf < 4; ++mf)
            af[mf] = *reinterpret_cast<const shortx8*>(base + (wm*4 + mf)*1024 + soff);
        #pragma unroll
        for (int nf = 0; nf < 4; ++nf)
            bf[nf] = *reinterpret_cast<const shortx8*>(base + 16384 + (wn*4 + nf)*1024 + soff);
        LGKM0();

        __builtin_amdgcn_s_setprio(1);
        #pragma unroll
        for (int mf = 0; mf < 4; ++mf)
            #pragma unroll
            for (int nf = 0; nf < 4; ++nf)
                acc[mf][nf] = __builtin_amdgcn_mfma_f32_16x16x32_bf16(af[mf], bf[nf], acc[mf][nf], 0, 0, 0);
        __builtin_amdgcn_s_setprio(0);

        if (T + 2 < NKT)      { VMC(3); SBAR(); }   // own T+1 stages landed; all waves
        else if (T + 1 < NKT) { VMC(0); SBAR(); }   // tail drain
    }

    // ---- epilogue: sigmoid(gate)*value -> padded LDS transpose -> store ----
    __syncthreads();
    unsigned short* ep = reinterpret_cast<unsigned short*>(lds);  // [256][LDSE]
    #pragma unroll
    for (int p = 0; p < 2; ++p){
        const int el = wn*32 + p*16 + fr;          // 0..63 (e-col within patch)
        const float rbe = rbias[nt*64 + el];
        const float vbe = vbias[nt*64 + el];
        #pragma unroll
        for (int mf = 0; mf < 4; ++mf){
            const int rbase = wm*64 + mf*16 + fq*4;
            f32x4 ga = acc[mf][2*p], va = acc[mf][2*p+1];
            #pragma unroll
            for (int q = 0; q < 4; ++q){
                const float g = sigmoidf_fast(ga[q] + rbe);
                ep[(rbase + q)*LDSE + el] = f2bf(g*(va[q] + vbe));
            }
        }
    }
    __syncthreads();
    #pragma unroll
    for (int p = 0; p < 4; ++p){
        const int r  = p*64 + (tid >> 3);
        const int c8 = tid & 7;
        shortx8 val = *reinterpret_cast<const shortx8*>(&ep[r*LDSE + c8*8]);
        *reinterpret_cast<shortx8*>(&gv[(size_t)(m0 + r)*DIM + nt*64 + c8*8]) = val;
    }
}

// ---------------- K6: LN2 + residual (wave-per-row) ----------------
__global__ __launch_bounds__(256) void k_ln2_res(
    const unsigned short* __restrict__ gvb, const unsigned short* __restrict__ shifted,
    const float* __restrict__ g2, const float* __restrict__ b2,
    float* __restrict__ out)
{
    const int tid = threadIdx.x, lane = tid & 63, wid = tid >> 6;
    const int row = blockIdx.x*4 + wid;

    const shortx4* GV = reinterpret_cast<const shortx4*>(gvb) + (size_t)row*256;
    const shortx4* SH = reinterpret_cast<const shortx4*>(shifted) + (size_t)row*256;

    f32x4 v[4];
    float s = 0.f, s2 = 0.f;
    #pragma unroll
    for (int j = 0; j < 4; ++j){
        f32x4 x = unpack4(GV[j*64 + lane]);
        v[j] = x;
        s  += x.x+x.y+x.z+x.w;
        s2 += x.x*x.x + x.y*x.y + x.z*x.z + x.w*x.w;
    }
    #pragma unroll
    for (int off = 1; off < 64; off <<= 1){
        s  += __shfl_xor(s,  off, 64);
        s2 += __shfl_xor(s2, off, 64);
    }
    const float mean = s * (1.0f/DIM);
    const float rstd = rsqrtf(s2*(1.0f/DIM) - mean*mean + 1e-5f);
    f32x4* O = reinterpret_cast<f32x4*>(out) + (size_t)row*256;
    #pragma unroll
    for (int j = 0; j < 4; ++j){
        f32x4 gg = reinterpret_cast<const f32x4*>(g2)[j*64 + lane];
        f32x4 bb = reinterpret_cast<const f32x4*>(b2)[j*64 + lane];
        f32x4 sh = unpack4(SH[j*64 + lane]);
        O[j*64 + lane] = sh + (v[j] - mean)*rstd*gg + bb;
    }
}

extern "C" void kernel_launch(void* const* d_in, const int* in_sizes, int n_in,
                              void* d_out, int out_size, void* d_ws, size_t ws_size,
                              hipStream_t stream)
{
    (void)in_sizes; (void)n_in; (void)out_size; (void)ws_size;
    const float* x     = (const float*)d_in[0];
    const float* xprev = (const float*)d_in[1];
    const float* mu    = (const float*)d_in[2];
    const float* dw    = (const float*)d_in[3];
    const float* db    = (const float*)d_in[4];
    const float* ln1g  = (const float*)d_in[5];
    const float* ln1b  = (const float*)d_in[6];
    const float* Wr    = (const float*)d_in[7];
    const float* Wrb   = (const float*)d_in[8];
    const float* Wv    = (const float*)d_in[9];
    const float* Wvb   = (const float*)d_in[10];
    const float* ln2g  = (const float*)d_in[11];
    const float* ln2b  = (const float*)d_in[12];
    float* out = (float*)d_out;

    char* ws = (char*)d_ws;
    size_t off = 0;
    auto alloc = [&](size_t bytes) -> void* {
        void* p = ws + off;
        off += (bytes + 255) & ~(size_t)255;
        return p;
    };
    unsigned short* shifted = (unsigned short*)alloc((size_t)NROWS*DIM*2);
    unsigned short* b_local = (unsigned short*)alloc((size_t)NROWS*DIM*2);
    unsigned short* merged  = (unsigned short*)alloc((size_t)NROWS*DIM*2);
    unsigned short* carryB  = (unsigned short*)alloc((size_t)BATCH*NCH*DIM*2);
    unsigned short* Wcat    = (unsigned short*)alloc((size_t)2048*1024*2);
    float* a_local          = (float*)alloc((size_t)NROWS*4);
    float* cumP             = (float*)alloc((size_t)NROWS*4);
    float* carryA           = (float*)alloc((size_t)BATCH*NCH*4);
    unsigned short* gvbuf   = b_local;   // b_local dead after k_fix_ln1

    hipLaunchKernelGGL(k_shift_scan, dim3(576),  dim3(256), 0, stream,
                       x, xprev, mu, dw, db, Wr, Wv, Wcat, shifted, b_local, a_local, cumP);
    hipLaunchKernelGGL(k_combine,    dim3(16),   dim3(64),  0, stream,
                       b_local, a_local, cumP, carryA, carryB);
    hipLaunchKernelGGL(k_fix_ln1,    dim3(4096), dim3(256), 0, stream,
                       b_local, a_local, cumP, carryA, carryB, ln1g, ln1b, merged);
    hipLaunchKernelGGL(k_gemm,       dim3(1024), dim3(512), 0, stream,
                       merged, Wcat, Wrb, Wvb, gvbuf);
    hipLaunchKernelGGL(k_ln2_res,    dim3(4096), dim3(256), 0, stream,
                       gvbuf, shifted, ln2g, ln2b, out);
}